// Round 15
// baseline (328.785 us; speedup 1.0000x reference)
//
#include <hip/hip_runtime.h>
#include <math.h>

constexpr int Bq  = 2;
constexpr int Tq  = 1024;
constexpr int HTq = 48;
constexpr float SCALE = 0.125f;     // 64^-0.5
constexpr float EOFF = 8.0f;        // fixed softmax offset (shift-invariant)

typedef __attribute__((ext_vector_type(8))) short short8;
typedef __attribute__((ext_vector_type(4))) float f32x4;

__device__ inline unsigned short f2bf(float x) {
    unsigned u = __float_as_uint(x);
    return (unsigned short)((u + 0x7FFF + ((u >> 16) & 1)) >> 16);
}

__device__ inline unsigned umax_(unsigned a, unsigned b) { return a > b ? a : b; }
__device__ inline unsigned umin_(unsigned a, unsigned b) { return a > b ? b : a; }

// async global->LDS, 16B per lane; LDS dest = wave-uniform base + lane*16
__device__ inline void gload_lds16(const unsigned short* g, unsigned short* l) {
    __builtin_amdgcn_global_load_lds(
        (const __attribute__((address_space(1))) void*)g,
        (__attribute__((address_space(3))) void*)l,
        16, 0, 0);
}

// exact 3-plane bf16 split: x = p0 + p1 + p2 + O(2^-27 |x|)
__device__ inline void split3(float x, unsigned short& p0, unsigned short& p1, unsigned short& p2) {
    p0 = f2bf(x);
    float f0 = __uint_as_float((unsigned)p0 << 16);
    float r0 = x - f0;
    p1 = f2bf(r0);
    float f1 = __uint_as_float((unsigned)p1 << 16);
    float r1 = r0 - f1;
    p2 = f2bf(r1);
}

// exact-erf GELU via Abramowitz-Stegun 7.1.26 (|eps_erf| <= 1.5e-7)
__device__ inline float gelu_f(float x) {
    float z = 0.70710678118654752f * x;
    float az = fabsf(z);
    float t = __frcp_rn(1.0f + 0.3275911f * az);
    float poly = t * (0.254829592f + t * (-0.284496736f + t * (1.421413741f
               + t * (-1.453152027f + t * 1.061405429f))));
    float er = 1.0f - poly * __expf(-az * az);
    er = (z < 0.0f) ? -er : er;
    return 0.5f * x * (1.0f + er);
}

// ---------------------------------------------------------------------------
// Merged prep: blocks [0,128) trig+kbias+V cvt; [128,488) weight fold+split;
// [488,2024) activation split.  Bodies byte-identical to round 14 kernels.
// ---------------------------------------------------------------------------
__global__ __launch_bounds__(256) void prep_kernel(
    float* __restrict__ trig, const float* __restrict__ WKb,
    const float* __restrict__ wA, float* __restrict__ bcat,
    const float* __restrict__ V1w, const float* __restrict__ V2w,
    unsigned short* __restrict__ vb16,
    const float* __restrict__ WQw, const float* __restrict__ WKw,
    const float* __restrict__ wbias, unsigned short* __restrict__ Wsp,
    const float* __restrict__ A, const float* __restrict__ X,
    unsigned short* __restrict__ Asp, unsigned short* __restrict__ Xsp)
{
    const size_t WPL = (size_t)4608 * 768;
    const size_t APL = (size_t)2048 * 768;
    __shared__ float sw[64][132];
    __shared__ float sk[64][65];
    int bid = blockIdx.x;
    int tid = threadIdx.x;

    if (bid < 128) {
        int i = bid * 256 + tid;   // 32768
        int t = i >> 5, f = i & 31;
        float invf = powf(10000.0f, -(float)f * (1.0f / 32.0f));
        float ang = (float)t * invf;
        trig[i] = cosf(ang);
        trig[32768 + i] = sinf(ang);
        if (i < 768) {
            int hb = i >> 6, el = i & 63;
            float acc = 0.0f;
            for (int d = 0; d < 64; d++) {
                float s = wA[d * 64 + el] - wA[el * 64 + d];
                acc += WKb[hb * 64 + d] * s;
            }
            bcat[i] = WKb[i] + acc;
        } else if (i < 1536) {
            bcat[i] = WKb[i - 768];
        }
        if (i < 8192) {
            float4 v = (i < 4096) ? ((const float4*)V1w)[i] : ((const float4*)V2w)[i - 4096];
            ushort4 o;
            o.x = f2bf(v.x); o.y = f2bf(v.y); o.z = f2bf(v.z); o.w = f2bf(v.w);
            ((ushort4*)vb16)[i] = o;
        }
        return;
    }
    if (bid < 488) {
        int id = bid - 128;
        int hb_ = id / 6, cb = id % 6;
        int mode = (hb_ < 48) ? 0 : 1;
        int h = mode ? hb_ - 48 : hb_;
        const float* Wsrc = mode ? WKw : WQw;
        const float* Wh = Wsrc + (size_t)h * 64 * 768 + cb * 128;
        for (int l = tid; l < 64 * 32; l += 256) {
            int d = l >> 5, c4 = l & 31;
            *(float4*)&sw[d][c4 * 4] = *(const float4*)(Wh + (size_t)d * 768 + c4 * 4);
        }
        for (int l = tid; l < 4096; l += 256) {
            int d = l >> 6, e = l & 63;
            sk[d][e] = wA[l] - wA[e * 64 + d];
        }
        __syncthreads();
        int tx = tid & 15, ty = tid >> 4;
        float acc4[4][8] = {};
        for (int d = 0; d < 64; d++) {
            float s0 = sk[d][ty * 4 + 0], s1 = sk[d][ty * 4 + 1];
            float s2 = sk[d][ty * 4 + 2], s3 = sk[d][ty * 4 + 3];
            float w_[8];
            *(float4*)&w_[0] = *(const float4*)&sw[d][tx * 8];
            *(float4*)&w_[4] = *(const float4*)&sw[d][tx * 8 + 4];
            #pragma unroll
            for (int j = 0; j < 8; j++) {
                acc4[0][j] += s0 * w_[j];
                acc4[1][j] += s1 * w_[j];
                acc4[2][j] += s2 * w_[j];
                acc4[3][j] += s3 * w_[j];
            }
        }
        #pragma unroll
        for (int i = 0; i < 4; i++) {
            int e = ty * 4 + i;
            float scale = (mode == 0) ? (1.0f + wbias[h * 64 + e]) : 1.0f;
            size_t row = (mode == 0) ? (size_t)(h * 64 + e) : (size_t)(3072 + h * 64 + e);
            #pragma unroll
            for (int j = 0; j < 8; j++) {
                int cl = tx * 8 + j;
                float wv = sw[e][cl] * scale + acc4[i][j];
                unsigned short p0, p1, p2;
                split3(wv, p0, p1, p2);
                size_t idx = row * 768 + cb * 128 + cl;
                Wsp[idx] = p0; Wsp[WPL + idx] = p1; Wsp[2 * WPL + idx] = p2;
            }
            if (mode == 1) {
                size_t row2 = (size_t)(3840 + h * 64 + e);
                #pragma unroll
                for (int j = 0; j < 8; j++) {
                    int cl = tx * 8 + j;
                    unsigned short p0, p1, p2;
                    split3(sw[e][cl], p0, p1, p2);
                    size_t idx = row2 * 768 + cb * 128 + cl;
                    Wsp[idx] = p0; Wsp[WPL + idx] = p1; Wsp[2 * WPL + idx] = p2;
                }
            }
        }
        return;
    }
    {
        int i = (bid - 488) * 256 + tid;   // 393216 quads
        if (i >= 393216) return;
        float4 va = ((const float4*)A)[i];
        float4 vx = ((const float4*)X)[i];
        ushort4 a0, a1, a2, x0, x1, x2;
        split3(va.x, a0.x, a1.x, a2.x); split3(va.y, a0.y, a1.y, a2.y);
        split3(va.z, a0.z, a1.z, a2.z); split3(va.w, a0.w, a1.w, a2.w);
        split3(vx.x, x0.x, x1.x, x2.x); split3(vx.y, x0.y, x1.y, x2.y);
        split3(vx.z, x0.z, x1.z, x2.z); split3(vx.w, x0.w, x1.w, x2.w);
        ((ushort4*)(Asp))[i] = a0;
        ((ushort4*)(Asp + APL))[i] = a1;
        ((ushort4*)(Asp + 2 * APL))[i] = a2;
        ((ushort4*)(Xsp))[i] = x0;
        ((ushort4*)(Xsp + APL))[i] = x1;
        ((ushort4*)(Xsp + 2 * APL))[i] = x2;
    }
}

// ---------------------------------------------------------------------------
// Projection GEMM v2: split-precision bf16 MFMA, DOUBLE-BUFFERED 2-phase
// pipeline — stage(next buffer) issued BEFORE compute(current), ONE barrier
// per K-step (implicit vmcnt(0) lands after ~48 MFMA of cover).  Same data,
// same MFMA order as round 11-14 -> bitwise-identical output.  96 KB LDS.
// ---------------------------------------------------------------------------
__global__ __launch_bounds__(512) void proj_mfma_kernel(
    const unsigned short* __restrict__ Asp, const unsigned short* __restrict__ Xsp,
    const unsigned short* __restrict__ Wsp, const float* __restrict__ bcat,
    const float* __restrict__ trig, float* __restrict__ Qr, float* __restrict__ O2)
{
    const size_t APL = (size_t)2048 * 768;
    const size_t WPL = (size_t)4608 * 768;
    const int BUFO = 3 * 128 * 32;     // 12288 ushorts per buffer
    __shared__ unsigned short sA[2 * 3 * 128 * 32];
    __shared__ unsigned short sB[2 * 3 * 128 * 32];
    int bid = blockIdx.x;
    int swz = (bid & 7) * 72 + (bid >> 3);
    int nb = swz >> 4;
    int mb = swz & 15;
    bool isQ = (nb < 24);
    const unsigned short* Ab = isQ ? Asp : Xsp;
    int m0 = mb * 128, n0 = nb * 128;
    int tid = threadIdx.x;
    int w = tid >> 6, lane = tid & 63;
    int wm = w & 1, wn = w >> 1;
    int rf = lane & 15, kg = lane >> 4;
    int mbase = m0 + wm * 64;

    int srcslot = (lane & 3) ^ ((lane >> 3) & 3);
    const unsigned short* gsrcA[3];
    const unsigned short* gsrcB[3];
    unsigned short* ldstA[3];
    unsigned short* ldstB[3];
    #pragma unroll
    for (int i = 0; i < 3; i++) {
        int reg = w + i * 8;
        int p = reg >> 3, rg = reg & 7;
        int row = rg * 16 + (lane >> 2);
        gsrcA[i] = Ab  + (size_t)p * APL + (size_t)(m0 + row) * 768 + srcslot * 8;
        gsrcB[i] = Wsp + (size_t)p * WPL + (size_t)(n0 + row) * 768 + srcslot * 8;
        ldstA[i] = &sA[p * 4096 + rg * 512];
        ldstB[i] = &sB[p * 4096 + rg * 512];
    }

    auto stage = [&](int bs, int k0) {
        #pragma unroll
        for (int i = 0; i < 3; i++) {
            gload_lds16(gsrcA[i] + k0, ldstA[i] + bs * BUFO);
            gload_lds16(gsrcB[i] + k0, ldstB[i] + bs * BUFO);
        }
    };

    f32x4 acc[4][2] = {};
    stage(0, 0);
    __syncthreads();
    int cur = 0;
    for (int step = 0; step < 24; step++) {
        if (step < 23) stage(cur ^ 1, (step + 1) * 32);

        const unsigned short* bA = &sA[cur * BUFO];
        const unsigned short* bB = &sB[cur * BUFO];
        short8 a0[4], a1[4], a2[4], b0[2], b1[2], b2[2];
        #pragma unroll
        for (int mi = 0; mi < 4; mi++) {
            int row = wm * 64 + mi * 16 + rf;
            a0[mi] = *(const short8*)&bA[0 * 4096 + row * 32 + ((kg ^ ((row >> 1) & 3)) * 8)];
        }
        #pragma unroll
        for (int nj = 0; nj < 2; nj++) {
            int row = wn * 32 + nj * 16 + rf;
            b0[nj] = *(const short8*)&bB[0 * 4096 + row * 32 + ((kg ^ ((row >> 1) & 3)) * 8)];
        }
        __builtin_amdgcn_s_setprio(1);
        #pragma unroll
        for (int mi = 0; mi < 4; mi++)
            #pragma unroll
            for (int nj = 0; nj < 2; nj++)
                acc[mi][nj] = __builtin_amdgcn_mfma_f32_16x16x32_bf16(a0[mi], b0[nj], acc[mi][nj], 0, 0, 0);
        __builtin_amdgcn_s_setprio(0);
        #pragma unroll
        for (int nj = 0; nj < 2; nj++) {
            int row = wn * 32 + nj * 16 + rf;
            b1[nj] = *(const short8*)&bB[1 * 4096 + row * 32 + ((kg ^ ((row >> 1) & 3)) * 8)];
        }
        __builtin_amdgcn_s_setprio(1);
        #pragma unroll
        for (int mi = 0; mi < 4; mi++)
            #pragma unroll
            for (int nj = 0; nj < 2; nj++)
                acc[mi][nj] = __builtin_amdgcn_mfma_f32_16x16x32_bf16(a0[mi], b1[nj], acc[mi][nj], 0, 0, 0);
        __builtin_amdgcn_s_setprio(0);
        #pragma unroll
        for (int nj = 0; nj < 2; nj++) {
            int row = wn * 32 + nj * 16 + rf;
            b2[nj] = *(const short8*)&bB[2 * 4096 + row * 32 + ((kg ^ ((row >> 1) & 3)) * 8)];
        }
        __builtin_amdgcn_s_setprio(1);
        #pragma unroll
        for (int mi = 0; mi < 4; mi++)
            #pragma unroll
            for (int nj = 0; nj < 2; nj++)
                acc[mi][nj] = __builtin_amdgcn_mfma_f32_16x16x32_bf16(a0[mi], b2[nj], acc[mi][nj], 0, 0, 0);
        __builtin_amdgcn_s_setprio(0);
        #pragma unroll
        for (int mi = 0; mi < 4; mi++) {
            int row = wm * 64 + mi * 16 + rf;
            a1[mi] = *(const short8*)&bA[1 * 4096 + row * 32 + ((kg ^ ((row >> 1) & 3)) * 8)];
        }
        __builtin_amdgcn_s_setprio(1);
        #pragma unroll
        for (int mi = 0; mi < 4; mi++)
            #pragma unroll
            for (int nj = 0; nj < 2; nj++)
                acc[mi][nj] = __builtin_amdgcn_mfma_f32_16x16x32_bf16(a1[mi], b0[nj], acc[mi][nj], 0, 0, 0);
        #pragma unroll
        for (int mi = 0; mi < 4; mi++)
            #pragma unroll
            for (int nj = 0; nj < 2; nj++)
                acc[mi][nj] = __builtin_amdgcn_mfma_f32_16x16x32_bf16(a1[mi], b1[nj], acc[mi][nj], 0, 0, 0);
        __builtin_amdgcn_s_setprio(0);
        #pragma unroll
        for (int mi = 0; mi < 4; mi++) {
            int row = wm * 64 + mi * 16 + rf;
            a2[mi] = *(const short8*)&bA[2 * 4096 + row * 32 + ((kg ^ ((row >> 1) & 3)) * 8)];
        }
        __builtin_amdgcn_s_setprio(1);
        #pragma unroll
        for (int mi = 0; mi < 4; mi++)
            #pragma unroll
            for (int nj = 0; nj < 2; nj++)
                acc[mi][nj] = __builtin_amdgcn_mfma_f32_16x16x32_bf16(a2[mi], b0[nj], acc[mi][nj], 0, 0, 0);
        __builtin_amdgcn_s_setprio(0);

        __syncthreads();   // drains vmcnt(0): prefetched buffer ready; readers done
        cur ^= 1;
    }

    if (isQ) {
        #pragma unroll
        for (int mi = 0; mi < 4; mi++) {
            #pragma unroll
            for (int r = 0; r < 4; r++) {
                int m = mbase + mi * 16 + kg * 4 + r;
                int b_ = m >> 10, t = m & 1023;
                #pragma unroll
                for (int nj = 0; nj < 2; nj++) {
                    int col_local = wn * 32 + nj * 16 + rf;
                    int h = nb * 2 + (col_local >> 6);
                    int d = col_local & 63;
                    int i = d >> 1;
                    float v = acc[mi][nj][r];
                    float pv = __shfl_xor(v, 1);
                    float c = trig[t * 32 + i];
                    float s = trig[32768 + t * 32 + i];
                    float outv = (rf & 1) ? (pv * s + v * c) : (v * c - pv * s);
                    int col = (rf & 1) ? (32 + i) : i;
                    size_t base = ((size_t)(b_ * 48 + h) * 1024 + t) * 64;
                    Qr[base + col] = outv;
                }
            }
        }
    } else {
        #pragma unroll
        for (int nj = 0; nj < 2; nj++) {
            int col = (n0 - 3072) + wn * 32 + nj * 16 + rf;
            float bv = bcat[col];
            #pragma unroll
            for (int mi = 0; mi < 4; mi++)
                #pragma unroll
                for (int r = 0; r < 4; r++) {
                    int m = mbase + mi * 16 + kg * 4 + r;
                    O2[(size_t)m * 1536 + col] = acc[mi][nj][r] + bv;
                }
        }
    }
}

// ---------------------------------------------------------------------------
__global__ void k_finish_kernel(const float* __restrict__ O2, const float* __restrict__ trig,
                                const float* __restrict__ wbias,
                                float* __restrict__ Kr, unsigned short* __restrict__ Kb16)
{
    int idx = blockIdx.x * 256 + threadIdx.x;   // 786432
    int pr = idx & 31;
    int tmp = idx >> 5;
    int hb = tmp % 12;
    int bt = tmp / 12;
    int t = bt & 1023, b = bt >> 10;
    const float* yx = O2 + (size_t)bt * 1536 + hb * 64 + pr * 2;
    float y0 = yx[0], y1 = yx[1];
    float x0 = yx[768], x1 = yx[769];
    float cv = trig[t * 32 + pr], sv = trig[32768 + t * 32 + pr];
    #pragma unroll
    for (int r = 0; r < 4; r++) {
        int h = hb + 12 * r;
        float b0 = wbias[h * 64 + 2 * pr], b1 = wbias[h * 64 + 2 * pr + 1];
        float wz0 = y0 + x0 * b0;
        float wz1 = y1 + x1 * b1;
        float lo = wz0 * cv - wz1 * sv;
        float hi = wz0 * sv + wz1 * cv;
        size_t base = ((size_t)(b * 48 + h) * 1024 + t) * 64;
        Kr[base + pr] = lo;
        Kr[base + 32 + pr] = hi;
        Kb16[base + pr] = f2bf(lo);
        Kb16[base + 32 + pr] = f2bf(hi);
    }
}

// ---------------------------------------------------------------------------
// Attention core v4 (round-13/14 verbatim): fixed-offset softmax + bitonic
// top-8 merge + exact fp32 re-score; setprio around MFMA clusters.
// ---------------------------------------------------------------------------
__global__ __launch_bounds__(256, 4) void attn_mfma_topk_kernel(
    const float* __restrict__ Qr, const float* __restrict__ Kr,
    const unsigned short* __restrict__ Kb, const float* __restrict__ sink,
    unsigned short* __restrict__ markerb, float* __restrict__ psink)
{
    const int bh = blockIdx.x;                 // 0..95
    const int y  = blockIdx.y;                 // 0..7
    const int w = threadIdx.x >> 6, lane = threadIdx.x & 63;
    const int rf = lane & 15, kg = lane >> 4;
    const int h = bh % HTq;
    const size_t rowbase = (size_t)bh * Tq;
    const unsigned short* Kbb = Kb + rowbase * 64;
    const float sk = sink[h];

    #pragma unroll 1
    for (int g = 0; g < 2; g++) {
        const int qb = g ? y : 15 - y;
        const int q0 = qb * 64 + w * 16;

        short8 a0, a1;
        {
            const float* qp = Qr + (rowbase + q0 + rf) * 64 + kg * 8;
            float4 u0 = *(const float4*)qp;
            float4 u1 = *(const float4*)(qp + 4);
            float4 u2 = *(const float4*)(qp + 32);
            float4 u3 = *(const float4*)(qp + 36);
            a0[0]=(short)f2bf(u0.x); a0[1]=(short)f2bf(u0.y); a0[2]=(short)f2bf(u0.z); a0[3]=(short)f2bf(u0.w);
            a0[4]=(short)f2bf(u1.x); a0[5]=(short)f2bf(u1.y); a0[6]=(short)f2bf(u1.z); a0[7]=(short)f2bf(u1.w);
            a1[0]=(short)f2bf(u2.x); a1[1]=(short)f2bf(u2.y); a1[2]=(short)f2bf(u2.z); a1[3]=(short)f2bf(u2.w);
            a1[4]=(short)f2bf(u3.x); a1[5]=(short)f2bf(u3.y); a1[6]=(short)f2bf(u3.z); a1[7]=(short)f2bf(u3.w);
        }

        float Z_[4];
        unsigned t_[4][4];
        #pragma unroll
        for (int r = 0; r < 4; r++) {
            Z_[r] = 0.0f;
            t_[r][0] = 0u; t_[r][1] = 0u; t_[r][2] = 0u; t_[r][3] = 0u;
        }

        short8 cA0[4], cA1[4], cB0[4], cB1[4];
        {
            const unsigned short* p = Kbb + (size_t)rf * 64 + kg * 8;
            #pragma unroll
            for (int kc = 0; kc < 4; kc++) {
                cA0[kc] = *(const short8*)(p + kc * 1024);
                cA1[kc] = *(const short8*)(p + kc * 1024 + 32);
            }
        }

        auto body = [&](short8 (&cb0)[4], short8 (&cb1)[4],
                        short8 (&nb0)[4], short8 (&nb1)[4], int tile) {
            f32x4 accs[4];
            __builtin_amdgcn_s_setprio(1);
            #pragma unroll
            for (int kc = 0; kc < 4; kc++) {
                f32x4 acc = {0.f, 0.f, 0.f, 0.f};
                acc = __builtin_amdgcn_mfma_f32_16x16x32_bf16(a0, cb0[kc], acc, 0, 0, 0);
                acc = __builtin_amdgcn_mfma_f32_16x16x32_bf16(a1, cb1[kc], acc, 0, 0, 0);
                accs[kc] = acc;
            }
            __builtin_amdgcn_s_setprio(0);
            const unsigned short* np = Kbb + (size_t)((tile + 1) * 64 + rf) * 64 + kg * 8;
            #pragma unroll
            for (int kc = 0; kc < 4; kc++) {
                nb0[kc] = *(const short8*)(np + kc * 1024);
                nb1[kc] = *(const short8*)(np + kc * 1024 + 32);
            }
            const int s0 = tile << 6;
            #pragma unroll
            for (int r = 0; r < 4; r++) {
                float s8[4];
                #pragma unroll
                for (int kc = 0; kc < 4; kc++) s8[kc] = fmaf(accs[kc][r], SCALE, -EOFF);
                #pragma unroll
                for (int kc = 0; kc < 4; kc++) {
                    unsigned u = __float_as_uint(s8[kc]);
                    unsigned key = u ^ ((unsigned)(((int)u) >> 31) | 0x80000000u);
                    unsigned c = (key & 0xFFFFFC00u) | (unsigned)(s0 + kc * 16 + rf);
                    unsigned n;
                    n = umax_(t_[r][0], c);  c = umin_(t_[r][0], c);  t_[r][0] = n;
                    n = umax_(t_[r][1], c);  c = umin_(t_[r][1], c);  t_[r][1] = n;
                    n = umax_(t_[r][2], c);  c = umin_(t_[r][2], c);  t_[r][2] = n;
                    t_[r][3] = umax_(t_[r][3], c);
                }
                float e0 = __expf(s8[0]), e1 = __expf(s8[1]);
                float e2 = __expf(s8[2]), e3 = __expf(s8[3]);
                Z_[r] += (e0 + e1) + (e2 + e3);
            }
        };

        int tile = 0;
        for (; tile + 1 < qb; tile += 2) {
            body(cA0, cA1, cB0, cB1, tile);
            body(cB0, cB1, cA0, cA1, tile + 1);
        }
        if (tile < qb) {
            body(cA0, cA1, cB0, cB1, tile);
            #pragma unroll
            for (int kc = 0; kc < 4; kc++) { cA0[kc] = cB0[kc]; cA1[kc] = cB1[kc]; }
        }

        // diagonal tile, masked
        {
            f32x4 accs[4];
            __builtin_amdgcn_s_setprio(1);
            #pragma unroll
            for (int kc = 0; kc < 4; kc++) {
                f32x4 acc = {0.f, 0.f, 0.f, 0.f};
                acc = __builtin_amdgcn_mfma_f32_16x16x32_bf16(a0, cA0[kc], acc, 0, 0, 0);
                acc = __builtin_amdgcn_mfma_f32_16x16x32_bf16(a1, cA1[kc], acc, 0, 0, 0);
                accs[kc] = acc;
            }
            __builtin_amdgcn_s_setprio(0);
            const int s0 = qb << 6;
            #pragma unroll
            for (int r = 0; r < 4; r++) {
                const int trow = q0 + kg * 4 + r;
                float ev[4];
                #pragma unroll
                for (int kc = 0; kc < 4; kc++) {
                    int k = s0 + kc * 16 + rf;
                    bool ok = (k <= trow);
                    float s8 = fmaf(accs[kc][r], SCALE, -EOFF);
                    unsigned u = __float_as_uint(s8);
                    unsigned key = u ^ ((unsigned)(((int)u) >> 31) | 0x80000000u);
                    unsigned c = (key & 0xFFFFFC00u) | (unsigned)k;
                    c = ok ? c : 0u;
                    unsigned n;
                    n = umax_(t_[r][0], c);  c = umin_(t_[r][0], c);  t_[r][0] = n;
                    n = umax_(t_[r][1], c);  c = umin_(t_[r][1], c);  t_[r][1] = n;
                    n = umax_(t_[r][2], c);  c = umin_(t_[r][2], c);  t_[r][2] = n;
                    t_[r][3] = umax_(t_[r][3], c);
                    ev[kc] = ok ? __expf(s8) : 0.0f;
                }
                Z_[r] += (ev[0] + ev[1]) + (ev[2] + ev[3]);
            }
        }

        const float esk = __expf(sk - EOFF);
        #pragma unroll 1
        for (int r = 0; r < 4; r++) {
            const int q = q0 + kg * 4 + r;
            float Z = Z_[r];
            #pragma unroll
            for (int off = 1; off < 16; off <<= 1) Z += __shfl_xor(Z, off);
            float Zf = Z + esk;

            // bitonic merge: 16 sorted-4 lists -> identical sorted top-8
            unsigned e0, e1, e2, e3, e4, e5, e6, e7;
            {
                unsigned A0 = t_[r][0], A1 = t_[r][1], A2 = t_[r][2], A3 = t_[r][3];
                unsigned B0 = (unsigned)__shfl_xor((int)A0, 1);
                unsigned B1 = (unsigned)__shfl_xor((int)A1, 1);
                unsigned B2 = (unsigned)__shfl_xor((int)A2, 1);
                unsigned B3 = (unsigned)__shfl_xor((int)A3, 1);
                unsigned y0 = umax_(A0, B3), y4 = umin_(A0, B3);
                unsigned y1 = umax_(A1, B2), y5 = umin_(A1, B2);
                unsigned y2 = umax_(A2, B1), y6 = umin_(A2, B1);
                unsigned y3 = umax_(A3, B0), y7 = umin_(A3, B0);
                unsigned z0 = umax_(y0, y2), z2 = umin_(y0, y2);
                unsigned z1 = umax_(y1, y3), z3 = umin_(y1, y3);
                unsigned z4 = umax_(y4, y6), z6 = umin_(y4, y6);
                unsigned z5 = umax_(y5, y7), z7 = umin_(y5, y7);
                e0 = umax_(z0, z1); e1 = umin_(z0, z1);
                e2 = umax_(z2, z3); e3 = umin_(z2, z3);
                e4 = umax_(z4, z5); e5 = umin_(z4, z5);
                e6 = umax_(z6, z7); e7 = umin_(z6, z7);
            }
            auto merge8 = [&](int off) {
                unsigned f0 = (unsigned)__shfl_xor((int)e0, off);
                unsigned f1 = (unsigned)__shfl_xor((int)e1, off);
                unsigned f2 = (unsigned)__shfl_xor((int)e2, off);
                unsigned f3 = (unsigned)__shfl_xor((int)e3, off);
                unsigned f4 = (unsigned)__shfl_xor((int)e4, off);
                unsigned f5 = (unsigned)__shfl_xor((int)e5, off);
                unsigned f6 = (unsigned)__shfl_xor((int)e6, off);
                unsigned f7 = (unsigned)__shfl_xor((int)e7, off);
                unsigned m0 = umax_(e0, f7), m1 = umax_(e1, f6);
                unsigned m2 = umax_(e2, f5), m3 = umax_(e3, f4);
                unsigned m4 = umax_(e4, f3), m5 = umax_(e5, f2);
                unsigned m6 = umax_(e6, f1), m7 = umax_(e7, f0);
                unsigned p0 = umax_(m0, m4), p4 = umin_(m0, m4);
                unsigned p1 = umax_(m1, m5), p5 = umin_(m1, m5);
                unsigned p2 = umax_(m2, m6), p6 = umin_(m2, m6);
                unsigned p3 = umax_(m3, m7), p7 = umin_(m3, m7);
                unsigned q0_ = umax_(p0, p2), q2_ = umin_(p0, p2);
                unsigned q1_ = umax_(p1, p3), q3_ = umin_(p1, p3);
                unsigned q4_ = umax_(p4, p6), q6_ = umin_(p4, p6);
                unsigned q5_ = umax_(p5, p7), q7_ = umin_(p5, p7);
                e0 = umax_(q0_, q1_); e1 = umin_(q0_, q1_);
                e2 = umax_(q2_, q3_); e3 = umin_(q2_, q3_);
                e4 = umax_(q4_, q5_); e5 = umin_(q4_, q5_);
                e6 = umax_(q6_, q7_); e7 = umin_(q6_, q7_);
            };
            merge8(2); merge8(4); merge8(8);
            unsigned ck[8] = {e0, e1, e2, e3, e4, e5, e6, e7};

            const float4 qv = *(const float4*)(Qr + (rowbase + q) * 64 + rf * 4);
            float sc[8]; int ci[8];
            #pragma unroll
            for (int c = 0; c < 8; c++) {
                bool valid = (ck[c] != 0u);
                int idx = (int)(ck[c] & 1023u);
                int lidx = valid ? idx : 0;
                const float4 kv = *(const float4*)(Kr + (rowbase + lidx) * 64 + rf * 4);
                float p = qv.x * kv.x + qv.y * kv.y + qv.z * kv.z + qv.w * kv.w;
                #pragma unroll
                for (int off = 1; off < 16; off <<= 1) p += __shfl_xor(p, off);
                sc[c] = valid ? p * SCALE : -1e30f;
                ci[c] = valid ? idx : -1;
            }
            float bv[4]; int bi[4];
            #pragma unroll
            for (int rd = 0; rd < 4; rd++) {
                float v = sc[0]; int id = ci[0];
                #pragma unroll
                for (int c = 1; c < 8; c++) {
                    bool take = (sc[c] > v) || ((sc[c] == v) && ((unsigned)ci[c] < (unsigned)id));
                    v = take ? sc[c] : v; id = take ? ci[c] : id;
                }
                bv[rd] = v; bi[rd] = id;
                #pragma unroll
                for (int c = 0; c < 8; c++) {
                    bool kill = (ci[c] == id) && (sc[c] == v);
                    sc[c] = kill ? -3e30f : sc[c];
                }
            }
            float e0f = __expf(bv[0] - EOFF), e1f = __expf(bv[1] - EOFF);
            float e2f = __expf(bv[2] - EOFF), e3f = __expf(bv[3] - EOFF);
            float wsum = e0f + e1f + e2f + e3f + Zf * 1e-9f;
            float w0 = e0f / wsum, w1 = e1f / wsum, w2 = e2f / wsum, w3 = e3f / wsum;
            int i0 = bi[0] < 0 ? 0 : bi[0];
            int i1 = bi[1] < 0 ? 0 : bi[1];
            int i2 = bi[2] < 0 ? 0 : bi[2];
            int i3 = bi[3] < 0 ? 0 : bi[3];
            const float4 k0 = *(const float4*)(Kr + (rowbase + i0) * 64 + rf * 4);
            const float4 k1 = *(const float4*)(Kr + (rowbase + i1) * 64 + rf * 4);
            const float4 k2 = *(const float4*)(Kr + (rowbase + i2) * 64 + rf * 4);
            const float4 k3 = *(const float4*)(Kr + (rowbase + i3) * 64 + rf * 4);
            float mx = w0 * k0.x + w1 * k1.x + w2 * k2.x + w3 * k3.x;
            float my = w0 * k0.y + w1 * k1.y + w2 * k2.y + w3 * k3.y;
            float mz = w0 * k0.z + w1 * k1.z + w2 * k2.z + w3 * k3.z;
            float mw = w0 * k0.w + w1 * k1.w + w2 * k2.w + w3 * k3.w;
            ushort4 mo;
            mo.x = f2bf(mx); mo.y = f2bf(my); mo.z = f2bf(mz); mo.w = f2bf(mw);
            *(ushort4*)(markerb + (rowbase + q) * 64 + rf * 4) = mo;
            if (rf == 0) psink[rowbase + q] = esk / Zf;
        }
    }
}

// ---------------------------------------------------------------------------
__global__ __launch_bounds__(256) void wo_transpose_kernel(
    const float* __restrict__ WOw, unsigned short* __restrict__ WOt)
{
    __shared__ float tl[64][65];
    int tid = threadIdx.x;
    int n = blockIdx.z;
    int c0 = blockIdx.x * 64, d0 = blockIdx.y * 64;
    const float* src = WOw + (size_t)n * 768 * 768;
    for (int l = tid; l < 64 * 16; l += 256) {
        int r = l >> 4, q = l & 15;
        float4 v = *(const float4*)(src + (size_t)(c0 + r) * 768 + d0 + q * 4);
        tl[r][q * 4 + 0] = v.x; tl[r][q * 4 + 1] = v.y;
        tl[r][q * 4 + 2] = v.z; tl[r][q * 4 + 3] = v.w;
    }
    __syncthreads();
    for (int l = tid; l < 64 * 16; l += 256) {
        int d = l >> 4, q = l & 15;
        ushort4 o;
        o.x = f2bf(tl[q * 4 + 0][d]); o.y = f2bf(tl[q * 4 + 1][d]);
        o.z = f2bf(tl[q * 4 + 2][d]); o.w = f2bf(tl[q * 4 + 3][d]);
        *(ushort4*)(WOt + (size_t)n * 768 * 768 + (size_t)(d0 + d) * 768 + c0 + q * 4) = o;
    }
}

// ---------------------------------------------------------------------------
// Fused MLP (round-14 verbatim): per-wave-private LDS, no barriers, setprio.
// ---------------------------------------------------------------------------
__global__ __launch_bounds__(256) void mlp_mfma_kernel(
    const unsigned short* __restrict__ markerb, const float* __restrict__ psink,
    const unsigned short* __restrict__ V1b16, const float* __restrict__ V1bias,
    const unsigned short* __restrict__ V2b16, const float* __restrict__ V2bias,
    const float* __restrict__ vnulls, unsigned short* __restrict__ ctxb)
{
    __shared__ float h_lds[4][16][65];
    int tid = threadIdx.x;
    int w = tid >> 6, lane = tid & 63;
    int rf = lane & 15, kg = lane >> 4;
    size_t r0 = (size_t)blockIdx.x * 64 + 16 * w;

    short8 a1[2];
    #pragma unroll
    for (int kk = 0; kk < 2; kk++)
        a1[kk] = *(const short8*)(markerb + (r0 + rf) * 64 + kk * 32 + kg * 8);

    f32x4 acc2[4] = {};
    for (int ch = 0; ch < 4; ch++) {
        f32x4 acc1[4] = {};
        __builtin_amdgcn_s_setprio(1);
        #pragma unroll
        for (int nj = 0; nj < 4; nj++)
            #pragma unroll
            for (int kk = 0; kk < 2; kk++) {
                short8 b1 = *(const short8*)(V1b16 + (size_t)(ch * 64 + nj * 16 + rf) * 64 + kk * 32 + kg * 8);
                acc1[nj] = __builtin_amdgcn_mfma_f32_16x16x32_bf16(a1[kk], b1, acc1[nj], 0, 0, 0);
            }
        __builtin_amdgcn_s_setprio(0);
        #pragma unroll
        for (int nj = 0; nj < 4; nj++) {
            float bb = V1bias[ch * 64 + nj * 16 + rf];
            #pragma unroll
            for (int r = 0; r < 4; r++) {
                float x = acc1[nj][r] + bb;
                h_lds[w][kg * 4 + r][nj * 16 + rf] = gelu_f(x);
            }
        }
        #pragma unroll
        for (int kk = 0; kk < 2; kk++) {
            const float* hp = &h_lds[w][rf][kk * 32 + kg * 8];
            float4 p0 = *(const float4*)hp;
            float4 p1 = *(const float4*)(hp + 4);
            short8 a2;
            a2[0] = (short)f2bf(p0.x); a2[1] = (short)f2bf(p0.y);
            a2[2] = (short)f2bf(p0.z); a2[3] = (short)f2bf(p0.w);
            a2[4] = (short)f2bf(p1.x); a2[5] = (short)f2bf(p1.y);
            a2[6] = (short)f2bf(p1.z); a2[7] = (short)f2bf(p1.w);
            __builtin_amdgcn_s_setprio(1);
            #pragma unroll
            for (int njo = 0; njo < 4; njo++) {
                short8 b2 = *(const short8*)(V2b16 + (size_t)(njo * 16 + rf) * 256 + ch * 64 + kk * 32 + kg * 8);
                acc2[njo] = __builtin_amdgcn_mfma_f32_16x16x32_bf16(a2, b2, acc2[njo], 0, 0, 0);
            }
            __builtin_amdgcn_s_setprio(0);
        }
    }
    #pragma unroll
    for (int r = 0; r < 4; r++) {
        size_t R = r0 + kg * 4 + r;
        int bh = (int)(R >> 10), t = (int)(R & 1023);
        int b = bh / 48, h = bh % 48;
        int n = h / 12, head = h % 12;
        float ps = psink[R];
        size_t base = ((size_t)((b * 4 + n) * 1024 + t)) * 768 + head * 64;
        #pragma unroll
        for (int njo = 0; njo < 4; njo++) {
            int d = njo * 16 + rf;
            float v = acc2[njo][r] + V2bias[d] + ps * vnulls[h * 64 + d];
            ctxb[base + d] = f2bf(v);
        }
    }
}

// ---------------------------------------------------------------------------
// WO projection (round-14 verbatim): BK=128, 16-slot XOR swizzle, setprio.
// ---------------------------------------------------------------------------
__global__ __launch_bounds__(256) void gemm_wo_mfma(
    const unsigned short* __restrict__ ctxb, const unsigned short* __restrict__ WOtb,
    const float* __restrict__ WOb, float* __restrict__ Out)
{
    __shared__ unsigned short sA[64 * 128];
    __shared__ unsigned short sB[64 * 128];
    int tid = threadIdx.x;
    int w = tid >> 6, lane = tid & 63;
    int wm = w >> 1, wn = w & 1;
    int rf = lane & 15, kg = lane >> 4;
    int m0 = blockIdx.x * 64, n0 = blockIdx.y * 64;
    int b = m0 >> 10, t0 = m0 & 1023;
    f32x4 acc[2][2] = {};
    for (int n = 0; n < 4; n++) {
        const unsigned short* Ab = ctxb + ((size_t)((b * 4 + n) * 1024 + t0)) * 768;
        const unsigned short* Bb = WOtb + (size_t)n * 768 * 768 + (size_t)n0 * 768;
        for (int k0 = 0; k0 < 768; k0 += 128) {
            __syncthreads();
            #pragma unroll
            for (int j = 0; j < 4; j++) {
                int e = tid + j * 256;
                int r = e >> 4, s = e & 15;
                int ss = s ^ (r & 15);
                *(short8*)&sA[r * 128 + ss * 8] = *(const short8*)(Ab + (size_t)r * 768 + k0 + s * 8);
                *(short8*)&sB[r * 128 + ss * 8] = *(const short8*)(Bb + (size_t)r * 768 + k0 + s * 8);
            }
            __syncthreads();
            __builtin_amdgcn_s_setprio(1);
            #pragma unroll
            for (int kk = 0; kk < 4; kk++) {
                int slot = kk * 4 + kg;
                int rA0 = wm * 32 + rf, rA1 = wm * 32 + 16 + rf;
                int rB0 = wn * 32 + rf, rB1 = wn * 32 + 16 + rf;
                short8 a0v = *(const short8*)&sA[rA0 * 128 + ((slot ^ (rA0 & 15)) * 8)];
                short8 a1v = *(const short8*)&sA[rA1 * 128 + ((slot ^ (rA1 & 15)) * 8)];
                short8 b0v = *(const short8*)&sB[rB0 * 128 + ((slot ^ (rB0 & 15)) * 8)];
                short8 b1v = *(const short8*)&sB[rB1 * 128 + ((slot ^ (rB1 & 15)) * 8)];
                acc[0][0] = __builtin_amdgcn_mfma_f32_16x16x32_bf16(a0v, b0v, acc[0][0], 0, 0, 0);
                acc[0][1] = __builtin_amdgcn_mfma_f32_16x16x32_bf16(a0v, b1v, acc[0][1], 0, 0, 0);
                acc[1][0] = __builtin_amdgcn_mfma_f32_16x16x32_bf16(a1v, b0v, acc[1][0], 0, 0, 0);
                acc[1][1] = __builtin_amdgcn_mfma_f32_16x16x32_bf16(a1v, b1v, acc[1][1], 0, 0, 0);
            }
            __builtin_amdgcn_s_setprio(0);
        }
    }
    #pragma unroll
    for (int nj = 0; nj < 2; nj++) {
        int col = n0 + wn * 32 + nj * 16 + rf;
        float bm = WOb[col] + WOb[768 + col] + WOb[1536 + col] + WOb[2304 + col];
        #pragma unroll
        for (int mi = 0; mi < 2; mi++)
            #pragma unroll
            for (int r = 0; r < 4; r++) {
                int row = m0 + wm * 32 + mi * 16 + kg * 4 + r;
                Out[(size_t)row * 768 + col] = 0.25f * (acc[mi][nj][r] + bm);
            }
    }
}

// ---------------------------------------------------------------------------
extern "C" void kernel_launch(void* const* d_in, const int* in_sizes, int n_in,
                              void* d_out, int out_size, void* d_ws, size_t ws_size,
                              hipStream_t stream) {
    const float* A      = (const float*)d_in[0];
    const float* X      = (const float*)d_in[1];
    const float* WKw    = (const float*)d_in[2];
    const float* WKb    = (const float*)d_in[3];
    const float* WQw    = (const float*)d_in[4];
    const float* wA     = (const float*)d_in[5];
    const float* wB     = (const float*)d_in[6];
    const float* sink   = (const float*)d_in[7];
    const float* vnulls = (const float*)d_in[8];
    const float* V1w    = (const float*)d_in[9];
    const float* V1b    = (const float*)d_in[10];
    const float* V2w    = (const float*)d_in[11];
    const float* V2b    = (const float*)d_in[12];
    const float* WOw    = (const float*)d_in[13];
    const float* WOb    = (const float*)d_in[14];
    float* out = (float*)d_out;
    (void)in_sizes; (void)n_in; (void)out_size; (void)ws_size;

    float* ws = (float*)d_ws;
    size_t off = 0;
    float* Qr   = ws + off;  off += 6291456;   // head-major fp32 Q (rope'd)
    float* Kr   = ws + off;  off += 6291456;   // head-major fp32 K (rope'd)
    float* trig = ws + off;  off += 65536;
    float* bcat = ws + off;  off += 2048;
    float* O2   = ws + off;  off += 3145728;   // [2048][1536]: y | x
    float* Wsp_f = ws + off; off += 5308416;   // 3 planes x 4608x768 ushort
    unsigned short* Wsp = (unsigned short*)Wsp_f;
    unsigned short* Asp = (unsigned short*)(ws + off); off += 2359296;  // 3 planes x 2048x768
    unsigned short* Xsp = (unsigned short*)(ws + off); off += 2359296;
    unsigned short* V1b16 = (unsigned short*)(ws + off); off += 16384; // V1+V2 bf16 (dedicated)
    unsigned short* V2b16 = V1b16 + 16384;
    // overlays (dead-buffer reuse) — audited lifetimes:
    //   markerb = O2 (FULL 3,145,728 floats; O2 dead after k_finish)
    //   Kb16 = Wsp floats [0, 3145728); psink = Wsp floats [3145728, 3244032)
    unsigned short* markerb = (unsigned short*)O2;
    unsigned short* Kb16 = Wsp;
    float* psink = Wsp_f + 3145728;
    unsigned short* WOtb  = Asp;                         // Asp dead after proj
    unsigned short* ctxb  = (unsigned short*)Qr;         // Qr dead after attn

    // merged prep: trig + kbias + V cvt | weight fold/split | activation split
    prep_kernel<<<2024, 256, 0, stream>>>(trig, WKb, wA, bcat, V1w, V2w, V1b16,
                                          WQw, WKw, wB, Wsp, A, X, Asp, Xsp);
    // split-precision MFMA projection, 2-phase double-buffered gload_lds
    proj_mfma_kernel<<<576, 512, 0, stream>>>(Asp, Xsp, Wsp, bcat, trig, Qr, O2);
    // finish K: per-h bias wedge term + rope -> Kr fp32 + Kb16 bf16
    k_finish_kernel<<<3072, 256, 0, stream>>>(O2, trig, wB, Kr, Kb16);
    // attention: MFMA scores, fixed-offset softmax, bitonic top-8 shortlist,
    // exact fp32 top-4
    attn_mfma_topk_kernel<<<dim3(96, 8), 256, 0, stream>>>(Qr, Kr, Kb16, sink, markerb, psink);
    // post-top-k smooth path (bf16/MFMA)
    wo_transpose_kernel<<<dim3(12, 12, 4), 256, 0, stream>>>(WOw, WOtb);
    mlp_mfma_kernel<<<1536, 256, 0, stream>>>(markerb, psink, V1b16, V1b, V2b16, V2b, vnulls, ctxb);
    gemm_wo_mfma<<<dim3(32, 12), 256, 0, stream>>>(ctxb, WOtb, WOb, out);
}

// Round 16
// 304.462 us; speedup vs baseline: 1.0799x; 1.0799x over previous
//
#include <hip/hip_runtime.h>
#include <math.h>

constexpr int Bq  = 2;
constexpr int Tq  = 1024;
constexpr int HTq = 48;
constexpr float SCALE = 0.125f;     // 64^-0.5
constexpr float EOFF = 8.0f;        // fixed softmax offset (shift-invariant)

typedef __attribute__((ext_vector_type(8))) short short8;
typedef __attribute__((ext_vector_type(4))) float f32x4;

__device__ inline unsigned short f2bf(float x) {
    unsigned u = __float_as_uint(x);
    return (unsigned short)((u + 0x7FFF + ((u >> 16) & 1)) >> 16);
}

__device__ inline unsigned umax_(unsigned a, unsigned b) { return a > b ? a : b; }
__device__ inline unsigned umin_(unsigned a, unsigned b) { return a > b ? b : a; }

// async global->LDS, 16B per lane; LDS dest = wave-uniform base + lane*16
__device__ inline void gload_lds16(const unsigned short* g, unsigned short* l) {
    __builtin_amdgcn_global_load_lds(
        (const __attribute__((address_space(1))) void*)g,
        (__attribute__((address_space(3))) void*)l,
        16, 0, 0);
}

// exact 3-plane bf16 split: x = p0 + p1 + p2 + O(2^-27 |x|)
__device__ inline void split3(float x, unsigned short& p0, unsigned short& p1, unsigned short& p2) {
    p0 = f2bf(x);
    float f0 = __uint_as_float((unsigned)p0 << 16);
    float r0 = x - f0;
    p1 = f2bf(r0);
    float f1 = __uint_as_float((unsigned)p1 << 16);
    float r1 = r0 - f1;
    p2 = f2bf(r1);
}

// exact-erf GELU via Abramowitz-Stegun 7.1.26 (|eps_erf| <= 1.5e-7)
__device__ inline float gelu_f(float x) {
    float z = 0.70710678118654752f * x;
    float az = fabsf(z);
    float t = __frcp_rn(1.0f + 0.3275911f * az);
    float poly = t * (0.254829592f + t * (-0.284496736f + t * (1.421413741f
               + t * (-1.453152027f + t * 1.061405429f))));
    float er = 1.0f - poly * __expf(-az * az);
    er = (z < 0.0f) ? -er : er;
    return 0.5f * x * (1.0f + er);
}

// ---------------------------------------------------------------------------
// Merged prep (round-15 verbatim): blocks [0,128) trig+kbias+V cvt;
// [128,488) weight fold+split; [488,2024) activation split.
// ---------------------------------------------------------------------------
__global__ __launch_bounds__(256) void prep_kernel(
    float* __restrict__ trig, const float* __restrict__ WKb,
    const float* __restrict__ wA, float* __restrict__ bcat,
    const float* __restrict__ V1w, const float* __restrict__ V2w,
    unsigned short* __restrict__ vb16,
    const float* __restrict__ WQw, const float* __restrict__ WKw,
    const float* __restrict__ wbias, unsigned short* __restrict__ Wsp,
    const float* __restrict__ A, const float* __restrict__ X,
    unsigned short* __restrict__ Asp, unsigned short* __restrict__ Xsp)
{
    const size_t WPL = (size_t)4608 * 768;
    const size_t APL = (size_t)2048 * 768;
    __shared__ float sw[64][132];
    __shared__ float sk[64][65];
    int bid = blockIdx.x;
    int tid = threadIdx.x;

    if (bid < 128) {
        int i = bid * 256 + tid;   // 32768
        int t = i >> 5, f = i & 31;
        float invf = powf(10000.0f, -(float)f * (1.0f / 32.0f));
        float ang = (float)t * invf;
        trig[i] = cosf(ang);
        trig[32768 + i] = sinf(ang);
        if (i < 768) {
            int hb = i >> 6, el = i & 63;
            float acc = 0.0f;
            for (int d = 0; d < 64; d++) {
                float s = wA[d * 64 + el] - wA[el * 64 + d];
                acc += WKb[hb * 64 + d] * s;
            }
            bcat[i] = WKb[i] + acc;
        } else if (i < 1536) {
            bcat[i] = WKb[i - 768];
        }
        if (i < 8192) {
            float4 v = (i < 4096) ? ((const float4*)V1w)[i] : ((const float4*)V2w)[i - 4096];
            ushort4 o;
            o.x = f2bf(v.x); o.y = f2bf(v.y); o.z = f2bf(v.z); o.w = f2bf(v.w);
            ((ushort4*)vb16)[i] = o;
        }
        return;
    }
    if (bid < 488) {
        int id = bid - 128;
        int hb_ = id / 6, cb = id % 6;
        int mode = (hb_ < 48) ? 0 : 1;
        int h = mode ? hb_ - 48 : hb_;
        const float* Wsrc = mode ? WKw : WQw;
        const float* Wh = Wsrc + (size_t)h * 64 * 768 + cb * 128;
        for (int l = tid; l < 64 * 32; l += 256) {
            int d = l >> 5, c4 = l & 31;
            *(float4*)&sw[d][c4 * 4] = *(const float4*)(Wh + (size_t)d * 768 + c4 * 4);
        }
        for (int l = tid; l < 4096; l += 256) {
            int d = l >> 6, e = l & 63;
            sk[d][e] = wA[l] - wA[e * 64 + d];
        }
        __syncthreads();
        int tx = tid & 15, ty = tid >> 4;
        float acc4[4][8] = {};
        for (int d = 0; d < 64; d++) {
            float s0 = sk[d][ty * 4 + 0], s1 = sk[d][ty * 4 + 1];
            float s2 = sk[d][ty * 4 + 2], s3 = sk[d][ty * 4 + 3];
            float w_[8];
            *(float4*)&w_[0] = *(const float4*)&sw[d][tx * 8];
            *(float4*)&w_[4] = *(const float4*)&sw[d][tx * 8 + 4];
            #pragma unroll
            for (int j = 0; j < 8; j++) {
                acc4[0][j] += s0 * w_[j];
                acc4[1][j] += s1 * w_[j];
                acc4[2][j] += s2 * w_[j];
                acc4[3][j] += s3 * w_[j];
            }
        }
        #pragma unroll
        for (int i = 0; i < 4; i++) {
            int e = ty * 4 + i;
            float scale = (mode == 0) ? (1.0f + wbias[h * 64 + e]) : 1.0f;
            size_t row = (mode == 0) ? (size_t)(h * 64 + e) : (size_t)(3072 + h * 64 + e);
            #pragma unroll
            for (int j = 0; j < 8; j++) {
                int cl = tx * 8 + j;
                float wv = sw[e][cl] * scale + acc4[i][j];
                unsigned short p0, p1, p2;
                split3(wv, p0, p1, p2);
                size_t idx = row * 768 + cb * 128 + cl;
                Wsp[idx] = p0; Wsp[WPL + idx] = p1; Wsp[2 * WPL + idx] = p2;
            }
            if (mode == 1) {
                size_t row2 = (size_t)(3840 + h * 64 + e);
                #pragma unroll
                for (int j = 0; j < 8; j++) {
                    int cl = tx * 8 + j;
                    unsigned short p0, p1, p2;
                    split3(sw[e][cl], p0, p1, p2);
                    size_t idx = row2 * 768 + cb * 128 + cl;
                    Wsp[idx] = p0; Wsp[WPL + idx] = p1; Wsp[2 * WPL + idx] = p2;
                }
            }
        }
        return;
    }
    {
        int i = (bid - 488) * 256 + tid;   // 393216 quads
        if (i >= 393216) return;
        float4 va = ((const float4*)A)[i];
        float4 vx = ((const float4*)X)[i];
        ushort4 a0, a1, a2, x0, x1, x2;
        split3(va.x, a0.x, a1.x, a2.x); split3(va.y, a0.y, a1.y, a2.y);
        split3(va.z, a0.z, a1.z, a2.z); split3(va.w, a0.w, a1.w, a2.w);
        split3(vx.x, x0.x, x1.x, x2.x); split3(vx.y, x0.y, x1.y, x2.y);
        split3(vx.z, x0.z, x1.z, x2.z); split3(vx.w, x0.w, x1.w, x2.w);
        ((ushort4*)(Asp))[i] = a0;
        ((ushort4*)(Asp + APL))[i] = a1;
        ((ushort4*)(Asp + 2 * APL))[i] = a2;
        ((ushort4*)(Xsp))[i] = x0;
        ((ushort4*)(Xsp + APL))[i] = x1;
        ((ushort4*)(Xsp + 2 * APL))[i] = x2;
    }
}

// ---------------------------------------------------------------------------
// Projection GEMM (ROUND-14 VERBATIM — measured 106 us): split-precision bf16
// MFMA, single 48 KB buffer, async global_load_lds staging, XOR-swizzled
// source, linear LDS dest.  The round-15 double-buffer variant regressed
// (96 KB LDS -> 1 block/CU, occupancy loss > pipeline gain; m132 mode).
// ---------------------------------------------------------------------------
__global__ __launch_bounds__(512) void proj_mfma_kernel(
    const unsigned short* __restrict__ Asp, const unsigned short* __restrict__ Xsp,
    const unsigned short* __restrict__ Wsp, const float* __restrict__ bcat,
    const float* __restrict__ trig, float* __restrict__ Qr, float* __restrict__ O2)
{
    const size_t APL = (size_t)2048 * 768;
    const size_t WPL = (size_t)4608 * 768;
    __shared__ unsigned short sA[3 * 128 * 32];
    __shared__ unsigned short sB[3 * 128 * 32];
    int bid = blockIdx.x;
    int swz = (bid & 7) * 72 + (bid >> 3);
    int nb = swz >> 4;
    int mb = swz & 15;
    bool isQ = (nb < 24);
    const unsigned short* Ab = isQ ? Asp : Xsp;
    int m0 = mb * 128, n0 = nb * 128;
    int tid = threadIdx.x;
    int w = tid >> 6, lane = tid & 63;
    int wm = w & 1, wn = w >> 1;
    int rf = lane & 15, kg = lane >> 4;
    int mbase = m0 + wm * 64;

    int srcslot = (lane & 3) ^ ((lane >> 3) & 3);
    const unsigned short* gsrcA[3];
    const unsigned short* gsrcB[3];
    unsigned short* ldstA[3];
    unsigned short* ldstB[3];
    #pragma unroll
    for (int i = 0; i < 3; i++) {
        int reg = w + i * 8;
        int p = reg >> 3, rg = reg & 7;
        int row = rg * 16 + (lane >> 2);
        gsrcA[i] = Ab  + (size_t)p * APL + (size_t)(m0 + row) * 768 + srcslot * 8;
        gsrcB[i] = Wsp + (size_t)p * WPL + (size_t)(n0 + row) * 768 + srcslot * 8;
        ldstA[i] = &sA[p * 4096 + rg * 512];
        ldstB[i] = &sB[p * 4096 + rg * 512];
    }

    f32x4 acc[4][2] = {};
    for (int k0 = 0; k0 < 768; k0 += 32) {
        __syncthreads();
        #pragma unroll
        for (int i = 0; i < 3; i++) {
            gload_lds16(gsrcA[i] + k0, ldstA[i]);
            gload_lds16(gsrcB[i] + k0, ldstB[i]);
        }
        __syncthreads();

        short8 a0[4], a1[4], a2[4], b0[2], b1[2], b2[2];
        #pragma unroll
        for (int mi = 0; mi < 4; mi++) {
            int row = wm * 64 + mi * 16 + rf;
            a0[mi] = *(const short8*)&sA[0 * 4096 + row * 32 + ((kg ^ ((row >> 1) & 3)) * 8)];
        }
        #pragma unroll
        for (int nj = 0; nj < 2; nj++) {
            int row = wn * 32 + nj * 16 + rf;
            b0[nj] = *(const short8*)&sB[0 * 4096 + row * 32 + ((kg ^ ((row >> 1) & 3)) * 8)];
        }
        #pragma unroll
        for (int mi = 0; mi < 4; mi++)
            #pragma unroll
            for (int nj = 0; nj < 2; nj++)
                acc[mi][nj] = __builtin_amdgcn_mfma_f32_16x16x32_bf16(a0[mi], b0[nj], acc[mi][nj], 0, 0, 0);
        #pragma unroll
        for (int nj = 0; nj < 2; nj++) {
            int row = wn * 32 + nj * 16 + rf;
            b1[nj] = *(const short8*)&sB[1 * 4096 + row * 32 + ((kg ^ ((row >> 1) & 3)) * 8)];
        }
        #pragma unroll
        for (int mi = 0; mi < 4; mi++)
            #pragma unroll
            for (int nj = 0; nj < 2; nj++)
                acc[mi][nj] = __builtin_amdgcn_mfma_f32_16x16x32_bf16(a0[mi], b1[nj], acc[mi][nj], 0, 0, 0);
        #pragma unroll
        for (int nj = 0; nj < 2; nj++) {
            int row = wn * 32 + nj * 16 + rf;
            b2[nj] = *(const short8*)&sB[2 * 4096 + row * 32 + ((kg ^ ((row >> 1) & 3)) * 8)];
        }
        #pragma unroll
        for (int mi = 0; mi < 4; mi++)
            #pragma unroll
            for (int nj = 0; nj < 2; nj++)
                acc[mi][nj] = __builtin_amdgcn_mfma_f32_16x16x32_bf16(a0[mi], b2[nj], acc[mi][nj], 0, 0, 0);
        #pragma unroll
        for (int mi = 0; mi < 4; mi++) {
            int row = wm * 64 + mi * 16 + rf;
            a1[mi] = *(const short8*)&sA[1 * 4096 + row * 32 + ((kg ^ ((row >> 1) & 3)) * 8)];
        }
        #pragma unroll
        for (int mi = 0; mi < 4; mi++)
            #pragma unroll
            for (int nj = 0; nj < 2; nj++)
                acc[mi][nj] = __builtin_amdgcn_mfma_f32_16x16x32_bf16(a1[mi], b0[nj], acc[mi][nj], 0, 0, 0);
        #pragma unroll
        for (int mi = 0; mi < 4; mi++)
            #pragma unroll
            for (int nj = 0; nj < 2; nj++)
                acc[mi][nj] = __builtin_amdgcn_mfma_f32_16x16x32_bf16(a1[mi], b1[nj], acc[mi][nj], 0, 0, 0);
        #pragma unroll
        for (int mi = 0; mi < 4; mi++) {
            int row = wm * 64 + mi * 16 + rf;
            a2[mi] = *(const short8*)&sA[2 * 4096 + row * 32 + ((kg ^ ((row >> 1) & 3)) * 8)];
        }
        #pragma unroll
        for (int mi = 0; mi < 4; mi++)
            #pragma unroll
            for (int nj = 0; nj < 2; nj++)
                acc[mi][nj] = __builtin_amdgcn_mfma_f32_16x16x32_bf16(a2[mi], b0[nj], acc[mi][nj], 0, 0, 0);
    }

    if (isQ) {
        #pragma unroll
        for (int mi = 0; mi < 4; mi++) {
            #pragma unroll
            for (int r = 0; r < 4; r++) {
                int m = mbase + mi * 16 + kg * 4 + r;
                int b_ = m >> 10, t = m & 1023;
                #pragma unroll
                for (int nj = 0; nj < 2; nj++) {
                    int col_local = wn * 32 + nj * 16 + rf;
                    int h = nb * 2 + (col_local >> 6);
                    int d = col_local & 63;
                    int i = d >> 1;
                    float v = acc[mi][nj][r];
                    float pv = __shfl_xor(v, 1);
                    float c = trig[t * 32 + i];
                    float s = trig[32768 + t * 32 + i];
                    float outv = (rf & 1) ? (pv * s + v * c) : (v * c - pv * s);
                    int col = (rf & 1) ? (32 + i) : i;
                    size_t base = ((size_t)(b_ * 48 + h) * 1024 + t) * 64;
                    Qr[base + col] = outv;
                }
            }
        }
    } else {
        #pragma unroll
        for (int nj = 0; nj < 2; nj++) {
            int col = (n0 - 3072) + wn * 32 + nj * 16 + rf;
            float bv = bcat[col];
            #pragma unroll
            for (int mi = 0; mi < 4; mi++)
                #pragma unroll
                for (int r = 0; r < 4; r++) {
                    int m = mbase + mi * 16 + kg * 4 + r;
                    O2[(size_t)m * 1536 + col] = acc[mi][nj][r] + bv;
                }
        }
    }
}

// ---------------------------------------------------------------------------
__global__ void k_finish_kernel(const float* __restrict__ O2, const float* __restrict__ trig,
                                const float* __restrict__ wbias,
                                float* __restrict__ Kr, unsigned short* __restrict__ Kb16)
{
    int idx = blockIdx.x * 256 + threadIdx.x;   // 786432
    int pr = idx & 31;
    int tmp = idx >> 5;
    int hb = tmp % 12;
    int bt = tmp / 12;
    int t = bt & 1023, b = bt >> 10;
    const float* yx = O2 + (size_t)bt * 1536 + hb * 64 + pr * 2;
    float y0 = yx[0], y1 = yx[1];
    float x0 = yx[768], x1 = yx[769];
    float cv = trig[t * 32 + pr], sv = trig[32768 + t * 32 + pr];
    #pragma unroll
    for (int r = 0; r < 4; r++) {
        int h = hb + 12 * r;
        float b0 = wbias[h * 64 + 2 * pr], b1 = wbias[h * 64 + 2 * pr + 1];
        float wz0 = y0 + x0 * b0;
        float wz1 = y1 + x1 * b1;
        float lo = wz0 * cv - wz1 * sv;
        float hi = wz0 * sv + wz1 * cv;
        size_t base = ((size_t)(b * 48 + h) * 1024 + t) * 64;
        Kr[base + pr] = lo;
        Kr[base + 32 + pr] = hi;
        Kb16[base + pr] = f2bf(lo);
        Kb16[base + 32 + pr] = f2bf(hi);
    }
}

// ---------------------------------------------------------------------------
// Attention core v4 (round-13/14 verbatim): fixed-offset softmax + bitonic
// top-8 merge + exact fp32 re-score; setprio around MFMA clusters.
// ---------------------------------------------------------------------------
__global__ __launch_bounds__(256, 4) void attn_mfma_topk_kernel(
    const float* __restrict__ Qr, const float* __restrict__ Kr,
    const unsigned short* __restrict__ Kb, const float* __restrict__ sink,
    unsigned short* __restrict__ markerb, float* __restrict__ psink)
{
    const int bh = blockIdx.x;                 // 0..95
    const int y  = blockIdx.y;                 // 0..7
    const int w = threadIdx.x >> 6, lane = threadIdx.x & 63;
    const int rf = lane & 15, kg = lane >> 4;
    const int h = bh % HTq;
    const size_t rowbase = (size_t)bh * Tq;
    const unsigned short* Kbb = Kb + rowbase * 64;
    const float sk = sink[h];

    #pragma unroll 1
    for (int g = 0; g < 2; g++) {
        const int qb = g ? y : 15 - y;
        const int q0 = qb * 64 + w * 16;

        short8 a0, a1;
        {
            const float* qp = Qr + (rowbase + q0 + rf) * 64 + kg * 8;
            float4 u0 = *(const float4*)qp;
            float4 u1 = *(const float4*)(qp + 4);
            float4 u2 = *(const float4*)(qp + 32);
            float4 u3 = *(const float4*)(qp + 36);
            a0[0]=(short)f2bf(u0.x); a0[1]=(short)f2bf(u0.y); a0[2]=(short)f2bf(u0.z); a0[3]=(short)f2bf(u0.w);
            a0[4]=(short)f2bf(u1.x); a0[5]=(short)f2bf(u1.y); a0[6]=(short)f2bf(u1.z); a0[7]=(short)f2bf(u1.w);
            a1[0]=(short)f2bf(u2.x); a1[1]=(short)f2bf(u2.y); a1[2]=(short)f2bf(u2.z); a1[3]=(short)f2bf(u2.w);
            a1[4]=(short)f2bf(u3.x); a1[5]=(short)f2bf(u3.y); a1[6]=(short)f2bf(u3.z); a1[7]=(short)f2bf(u3.w);
        }

        float Z_[4];
        unsigned t_[4][4];
        #pragma unroll
        for (int r = 0; r < 4; r++) {
            Z_[r] = 0.0f;
            t_[r][0] = 0u; t_[r][1] = 0u; t_[r][2] = 0u; t_[r][3] = 0u;
        }

        short8 cA0[4], cA1[4], cB0[4], cB1[4];
        {
            const unsigned short* p = Kbb + (size_t)rf * 64 + kg * 8;
            #pragma unroll
            for (int kc = 0; kc < 4; kc++) {
                cA0[kc] = *(const short8*)(p + kc * 1024);
                cA1[kc] = *(const short8*)(p + kc * 1024 + 32);
            }
        }

        auto body = [&](short8 (&cb0)[4], short8 (&cb1)[4],
                        short8 (&nb0)[4], short8 (&nb1)[4], int tile) {
            f32x4 accs[4];
            __builtin_amdgcn_s_setprio(1);
            #pragma unroll
            for (int kc = 0; kc < 4; kc++) {
                f32x4 acc = {0.f, 0.f, 0.f, 0.f};
                acc = __builtin_amdgcn_mfma_f32_16x16x32_bf16(a0, cb0[kc], acc, 0, 0, 0);
                acc = __builtin_amdgcn_mfma_f32_16x16x32_bf16(a1, cb1[kc], acc, 0, 0, 0);
                accs[kc] = acc;
            }
            __builtin_amdgcn_s_setprio(0);
            const unsigned short* np = Kbb + (size_t)((tile + 1) * 64 + rf) * 64 + kg * 8;
            #pragma unroll
            for (int kc = 0; kc < 4; kc++) {
                nb0[kc] = *(const short8*)(np + kc * 1024);
                nb1[kc] = *(const short8*)(np + kc * 1024 + 32);
            }
            const int s0 = tile << 6;
            #pragma unroll
            for (int r = 0; r < 4; r++) {
                float s8[4];
                #pragma unroll
                for (int kc = 0; kc < 4; kc++) s8[kc] = fmaf(accs[kc][r], SCALE, -EOFF);
                #pragma unroll
                for (int kc = 0; kc < 4; kc++) {
                    unsigned u = __float_as_uint(s8[kc]);
                    unsigned key = u ^ ((unsigned)(((int)u) >> 31) | 0x80000000u);
                    unsigned c = (key & 0xFFFFFC00u) | (unsigned)(s0 + kc * 16 + rf);
                    unsigned n;
                    n = umax_(t_[r][0], c);  c = umin_(t_[r][0], c);  t_[r][0] = n;
                    n = umax_(t_[r][1], c);  c = umin_(t_[r][1], c);  t_[r][1] = n;
                    n = umax_(t_[r][2], c);  c = umin_(t_[r][2], c);  t_[r][2] = n;
                    t_[r][3] = umax_(t_[r][3], c);
                }
                float e0 = __expf(s8[0]), e1 = __expf(s8[1]);
                float e2 = __expf(s8[2]), e3 = __expf(s8[3]);
                Z_[r] += (e0 + e1) + (e2 + e3);
            }
        };

        int tile = 0;
        for (; tile + 1 < qb; tile += 2) {
            body(cA0, cA1, cB0, cB1, tile);
            body(cB0, cB1, cA0, cA1, tile + 1);
        }
        if (tile < qb) {
            body(cA0, cA1, cB0, cB1, tile);
            #pragma unroll
            for (int kc = 0; kc < 4; kc++) { cA0[kc] = cB0[kc]; cA1[kc] = cB1[kc]; }
        }

        // diagonal tile, masked
        {
            f32x4 accs[4];
            __builtin_amdgcn_s_setprio(1);
            #pragma unroll
            for (int kc = 0; kc < 4; kc++) {
                f32x4 acc = {0.f, 0.f, 0.f, 0.f};
                acc = __builtin_amdgcn_mfma_f32_16x16x32_bf16(a0, cA0[kc], acc, 0, 0, 0);
                acc = __builtin_amdgcn_mfma_f32_16x16x32_bf16(a1, cA1[kc], acc, 0, 0, 0);
                accs[kc] = acc;
            }
            __builtin_amdgcn_s_setprio(0);
            const int s0 = qb << 6;
            #pragma unroll
            for (int r = 0; r < 4; r++) {
                const int trow = q0 + kg * 4 + r;
                float ev[4];
                #pragma unroll
                for (int kc = 0; kc < 4; kc++) {
                    int k = s0 + kc * 16 + rf;
                    bool ok = (k <= trow);
                    float s8 = fmaf(accs[kc][r], SCALE, -EOFF);
                    unsigned u = __float_as_uint(s8);
                    unsigned key = u ^ ((unsigned)(((int)u) >> 31) | 0x80000000u);
                    unsigned c = (key & 0xFFFFFC00u) | (unsigned)k;
                    c = ok ? c : 0u;
                    unsigned n;
                    n = umax_(t_[r][0], c);  c = umin_(t_[r][0], c);  t_[r][0] = n;
                    n = umax_(t_[r][1], c);  c = umin_(t_[r][1], c);  t_[r][1] = n;
                    n = umax_(t_[r][2], c);  c = umin_(t_[r][2], c);  t_[r][2] = n;
                    t_[r][3] = umax_(t_[r][3], c);
                    ev[kc] = ok ? __expf(s8) : 0.0f;
                }
                Z_[r] += (ev[0] + ev[1]) + (ev[2] + ev[3]);
            }
        }

        const float esk = __expf(sk - EOFF);
        #pragma unroll 1
        for (int r = 0; r < 4; r++) {
            const int q = q0 + kg * 4 + r;
            float Z = Z_[r];
            #pragma unroll
            for (int off = 1; off < 16; off <<= 1) Z += __shfl_xor(Z, off);
            float Zf = Z + esk;

            // bitonic merge: 16 sorted-4 lists -> identical sorted top-8
            unsigned e0, e1, e2, e3, e4, e5, e6, e7;
            {
                unsigned A0 = t_[r][0], A1 = t_[r][1], A2 = t_[r][2], A3 = t_[r][3];
                unsigned B0 = (unsigned)__shfl_xor((int)A0, 1);
                unsigned B1 = (unsigned)__shfl_xor((int)A1, 1);
                unsigned B2 = (unsigned)__shfl_xor((int)A2, 1);
                unsigned B3 = (unsigned)__shfl_xor((int)A3, 1);
                unsigned y0 = umax_(A0, B3), y4 = umin_(A0, B3);
                unsigned y1 = umax_(A1, B2), y5 = umin_(A1, B2);
                unsigned y2 = umax_(A2, B1), y6 = umin_(A2, B1);
                unsigned y3 = umax_(A3, B0), y7 = umin_(A3, B0);
                unsigned z0 = umax_(y0, y2), z2 = umin_(y0, y2);
                unsigned z1 = umax_(y1, y3), z3 = umin_(y1, y3);
                unsigned z4 = umax_(y4, y6), z6 = umin_(y4, y6);
                unsigned z5 = umax_(y5, y7), z7 = umin_(y5, y7);
                e0 = umax_(z0, z1); e1 = umin_(z0, z1);
                e2 = umax_(z2, z3); e3 = umin_(z2, z3);
                e4 = umax_(z4, z5); e5 = umin_(z4, z5);
                e6 = umax_(z6, z7); e7 = umin_(z6, z7);
            }
            auto merge8 = [&](int off) {
                unsigned f0 = (unsigned)__shfl_xor((int)e0, off);
                unsigned f1 = (unsigned)__shfl_xor((int)e1, off);
                unsigned f2 = (unsigned)__shfl_xor((int)e2, off);
                unsigned f3 = (unsigned)__shfl_xor((int)e3, off);
                unsigned f4 = (unsigned)__shfl_xor((int)e4, off);
                unsigned f5 = (unsigned)__shfl_xor((int)e5, off);
                unsigned f6 = (unsigned)__shfl_xor((int)e6, off);
                unsigned f7 = (unsigned)__shfl_xor((int)e7, off);
                unsigned m0 = umax_(e0, f7), m1 = umax_(e1, f6);
                unsigned m2 = umax_(e2, f5), m3 = umax_(e3, f4);
                unsigned m4 = umax_(e4, f3), m5 = umax_(e5, f2);
                unsigned m6 = umax_(e6, f1), m7 = umax_(e7, f0);
                unsigned p0 = umax_(m0, m4), p4 = umin_(m0, m4);
                unsigned p1 = umax_(m1, m5), p5 = umin_(m1, m5);
                unsigned p2 = umax_(m2, m6), p6 = umin_(m2, m6);
                unsigned p3 = umax_(m3, m7), p7 = umin_(m3, m7);
                unsigned q0_ = umax_(p0, p2), q2_ = umin_(p0, p2);
                unsigned q1_ = umax_(p1, p3), q3_ = umin_(p1, p3);
                unsigned q4_ = umax_(p4, p6), q6_ = umin_(p4, p6);
                unsigned q5_ = umax_(p5, p7), q7_ = umin_(p5, p7);
                e0 = umax_(q0_, q1_); e1 = umin_(q0_, q1_);
                e2 = umax_(q2_, q3_); e3 = umin_(q2_, q3_);
                e4 = umax_(q4_, q5_); e5 = umin_(q4_, q5_);
                e6 = umax_(q6_, q7_); e7 = umin_(q6_, q7_);
            };
            merge8(2); merge8(4); merge8(8);
            unsigned ck[8] = {e0, e1, e2, e3, e4, e5, e6, e7};

            const float4 qv = *(const float4*)(Qr + (rowbase + q) * 64 + rf * 4);
            float sc[8]; int ci[8];
            #pragma unroll
            for (int c = 0; c < 8; c++) {
                bool valid = (ck[c] != 0u);
                int idx = (int)(ck[c] & 1023u);
                int lidx = valid ? idx : 0;
                const float4 kv = *(const float4*)(Kr + (rowbase + lidx) * 64 + rf * 4);
                float p = qv.x * kv.x + qv.y * kv.y + qv.z * kv.z + qv.w * kv.w;
                #pragma unroll
                for (int off = 1; off < 16; off <<= 1) p += __shfl_xor(p, off);
                sc[c] = valid ? p * SCALE : -1e30f;
                ci[c] = valid ? idx : -1;
            }
            float bv[4]; int bi[4];
            #pragma unroll
            for (int rd = 0; rd < 4; rd++) {
                float v = sc[0]; int id = ci[0];
                #pragma unroll
                for (int c = 1; c < 8; c++) {
                    bool take = (sc[c] > v) || ((sc[c] == v) && ((unsigned)ci[c] < (unsigned)id));
                    v = take ? sc[c] : v; id = take ? ci[c] : id;
                }
                bv[rd] = v; bi[rd] = id;
                #pragma unroll
                for (int c = 0; c < 8; c++) {
                    bool kill = (ci[c] == id) && (sc[c] == v);
                    sc[c] = kill ? -3e30f : sc[c];
                }
            }
            float e0f = __expf(bv[0] - EOFF), e1f = __expf(bv[1] - EOFF);
            float e2f = __expf(bv[2] - EOFF), e3f = __expf(bv[3] - EOFF);
            float wsum = e0f + e1f + e2f + e3f + Zf * 1e-9f;
            float w0 = e0f / wsum, w1 = e1f / wsum, w2 = e2f / wsum, w3 = e3f / wsum;
            int i0 = bi[0] < 0 ? 0 : bi[0];
            int i1 = bi[1] < 0 ? 0 : bi[1];
            int i2 = bi[2] < 0 ? 0 : bi[2];
            int i3 = bi[3] < 0 ? 0 : bi[3];
            const float4 k0 = *(const float4*)(Kr + (rowbase + i0) * 64 + rf * 4);
            const float4 k1 = *(const float4*)(Kr + (rowbase + i1) * 64 + rf * 4);
            const float4 k2 = *(const float4*)(Kr + (rowbase + i2) * 64 + rf * 4);
            const float4 k3 = *(const float4*)(Kr + (rowbase + i3) * 64 + rf * 4);
            float mx = w0 * k0.x + w1 * k1.x + w2 * k2.x + w3 * k3.x;
            float my = w0 * k0.y + w1 * k1.y + w2 * k2.y + w3 * k3.y;
            float mz = w0 * k0.z + w1 * k1.z + w2 * k2.z + w3 * k3.z;
            float mw = w0 * k0.w + w1 * k1.w + w2 * k2.w + w3 * k3.w;
            ushort4 mo;
            mo.x = f2bf(mx); mo.y = f2bf(my); mo.z = f2bf(mz); mo.w = f2bf(mw);
            *(ushort4*)(markerb + (rowbase + q) * 64 + rf * 4) = mo;
            if (rf == 0) psink[rowbase + q] = esk / Zf;
        }
    }
}

// ---------------------------------------------------------------------------
__global__ __launch_bounds__(256) void wo_transpose_kernel(
    const float* __restrict__ WOw, unsigned short* __restrict__ WOt)
{
    __shared__ float tl[64][65];
    int tid = threadIdx.x;
    int n = blockIdx.z;
    int c0 = blockIdx.x * 64, d0 = blockIdx.y * 64;
    const float* src = WOw + (size_t)n * 768 * 768;
    for (int l = tid; l < 64 * 16; l += 256) {
        int r = l >> 4, q = l & 15;
        float4 v = *(const float4*)(src + (size_t)(c0 + r) * 768 + d0 + q * 4);
        tl[r][q * 4 + 0] = v.x; tl[r][q * 4 + 1] = v.y;
        tl[r][q * 4 + 2] = v.z; tl[r][q * 4 + 3] = v.w;
    }
    __syncthreads();
    for (int l = tid; l < 64 * 16; l += 256) {
        int d = l >> 4, q = l & 15;
        ushort4 o;
        o.x = f2bf(tl[q * 4 + 0][d]); o.y = f2bf(tl[q * 4 + 1][d]);
        o.z = f2bf(tl[q * 4 + 2][d]); o.w = f2bf(tl[q * 4 + 3][d]);
        *(ushort4*)(WOt + (size_t)n * 768 * 768 + (size_t)(d0 + d) * 768 + c0 + q * 4) = o;
    }
}

// ---------------------------------------------------------------------------
// Fused MLP (round-14 verbatim): per-wave-private LDS, no barriers, setprio.
// ---------------------------------------------------------------------------
__global__ __launch_bounds__(256) void mlp_mfma_kernel(
    const unsigned short* __restrict__ markerb, const float* __restrict__ psink,
    const unsigned short* __restrict__ V1b16, const float* __restrict__ V1bias,
    const unsigned short* __restrict__ V2b16, const float* __restrict__ V2bias,
    const float* __restrict__ vnulls, unsigned short* __restrict__ ctxb)
{
    __shared__ float h_lds[4][16][65];
    int tid = threadIdx.x;
    int w = tid >> 6, lane = tid & 63;
    int rf = lane & 15, kg = lane >> 4;
    size_t r0 = (size_t)blockIdx.x * 64 + 16 * w;

    short8 a1[2];
    #pragma unroll
    for (int kk = 0; kk < 2; kk++)
        a1[kk] = *(const short8*)(markerb + (r0 + rf) * 64 + kk * 32 + kg * 8);

    f32x4 acc2[4] = {};
    for (int ch = 0; ch < 4; ch++) {
        f32x4 acc1[4] = {};
        __builtin_amdgcn_s_setprio(1);
        #pragma unroll
        for (int nj = 0; nj < 4; nj++)
            #pragma unroll
            for (int kk = 0; kk < 2; kk++) {
                short8 b1 = *(const short8*)(V1b16 + (size_t)(ch * 64 + nj * 16 + rf) * 64 + kk * 32 + kg * 8);
                acc1[nj] = __builtin_amdgcn_mfma_f32_16x16x32_bf16(a1[kk], b1, acc1[nj], 0, 0, 0);
            }
        __builtin_amdgcn_s_setprio(0);
        #pragma unroll
        for (int nj = 0; nj < 4; nj++) {
            float bb = V1bias[ch * 64 + nj * 16 + rf];
            #pragma unroll
            for (int r = 0; r < 4; r++) {
                float x = acc1[nj][r] + bb;
                h_lds[w][kg * 4 + r][nj * 16 + rf] = gelu_f(x);
            }
        }
        #pragma unroll
        for (int kk = 0; kk < 2; kk++) {
            const float* hp = &h_lds[w][rf][kk * 32 + kg * 8];
            float4 p0 = *(const float4*)hp;
            float4 p1 = *(const float4*)(hp + 4);
            short8 a2;
            a2[0] = (short)f2bf(p0.x); a2[1] = (short)f2bf(p0.y);
            a2[2] = (short)f2bf(p0.z); a2[3] = (short)f2bf(p0.w);
            a2[4] = (short)f2bf(p1.x); a2[5] = (short)f2bf(p1.y);
            a2[6] = (short)f2bf(p1.z); a2[7] = (short)f2bf(p1.w);
            __builtin_amdgcn_s_setprio(1);
            #pragma unroll
            for (int njo = 0; njo < 4; njo++) {
                short8 b2 = *(const short8*)(V2b16 + (size_t)(njo * 16 + rf) * 256 + ch * 64 + kk * 32 + kg * 8);
                acc2[njo] = __builtin_amdgcn_mfma_f32_16x16x32_bf16(a2, b2, acc2[njo], 0, 0, 0);
            }
            __builtin_amdgcn_s_setprio(0);
        }
    }
    #pragma unroll
    for (int r = 0; r < 4; r++) {
        size_t R = r0 + kg * 4 + r;
        int bh = (int)(R >> 10), t = (int)(R & 1023);
        int b = bh / 48, h = bh % 48;
        int n = h / 12, head = h % 12;
        float ps = psink[R];
        size_t base = ((size_t)((b * 4 + n) * 1024 + t)) * 768 + head * 64;
        #pragma unroll
        for (int njo = 0; njo < 4; njo++) {
            int d = njo * 16 + rf;
            float v = acc2[njo][r] + V2bias[d] + ps * vnulls[h * 64 + d];
            ctxb[base + d] = f2bf(v);
        }
    }
}

// ---------------------------------------------------------------------------
// WO projection (round-14 verbatim): BK=128, 16-slot XOR swizzle, setprio.
// ---------------------------------------------------------------------------
__global__ __launch_bounds__(256) void gemm_wo_mfma(
    const unsigned short* __restrict__ ctxb, const unsigned short* __restrict__ WOtb,
    const float* __restrict__ WOb, float* __restrict__ Out)
{
    __shared__ unsigned short sA[64 * 128];
    __shared__ unsigned short sB[64 * 128];
    int tid = threadIdx.x;
    int w = tid >> 6, lane = tid & 63;
    int wm = w >> 1, wn = w & 1;
    int rf = lane & 15, kg = lane >> 4;
    int m0 = blockIdx.x * 64, n0 = blockIdx.y * 64;
    int b = m0 >> 10, t0 = m0 & 1023;
    f32x4 acc[2][2] = {};
    for (int n = 0; n < 4; n++) {
        const unsigned short* Ab = ctxb + ((size_t)((b * 4 + n) * 1024 + t0)) * 768;
        const unsigned short* Bb = WOtb + (size_t)n * 768 * 768 + (size_t)n0 * 768;
        for (int k0 = 0; k0 < 768; k0 += 128) {
            __syncthreads();
            #pragma unroll
            for (int j = 0; j < 4; j++) {
                int e = tid + j * 256;
                int r = e >> 4, s = e & 15;
                int ss = s ^ (r & 15);
                *(short8*)&sA[r * 128 + ss * 8] = *(const short8*)(Ab + (size_t)r * 768 + k0 + s * 8);
                *(short8*)&sB[r * 128 + ss * 8] = *(const short8*)(Bb + (size_t)r * 768 + k0 + s * 8);
            }
            __syncthreads();
            __builtin_amdgcn_s_setprio(1);
            #pragma unroll
            for (int kk = 0; kk < 4; kk++) {
                int slot = kk * 4 + kg;
                int rA0 = wm * 32 + rf, rA1 = wm * 32 + 16 + rf;
                int rB0 = wn * 32 + rf, rB1 = wn * 32 + 16 + rf;
                short8 a0v = *(const short8*)&sA[rA0 * 128 + ((slot ^ (rA0 & 15)) * 8)];
                short8 a1v = *(const short8*)&sA[rA1 * 128 + ((slot ^ (rA1 & 15)) * 8)];
                short8 b0v = *(const short8*)&sB[rB0 * 128 + ((slot ^ (rB0 & 15)) * 8)];
                short8 b1v = *(const short8*)&sB[rB1 * 128 + ((slot ^ (rB1 & 15)) * 8)];
                acc[0][0] = __builtin_amdgcn_mfma_f32_16x16x32_bf16(a0v, b0v, acc[0][0], 0, 0, 0);
                acc[0][1] = __builtin_amdgcn_mfma_f32_16x16x32_bf16(a0v, b1v, acc[0][1], 0, 0, 0);
                acc[1][0] = __builtin_amdgcn_mfma_f32_16x16x32_bf16(a1v, b0v, acc[1][0], 0, 0, 0);
                acc[1][1] = __builtin_amdgcn_mfma_f32_16x16x32_bf16(a1v, b1v, acc[1][1], 0, 0, 0);
            }
            __builtin_amdgcn_s_setprio(0);
        }
    }
    #pragma unroll
    for (int nj = 0; nj < 2; nj++) {
        int col = n0 + wn * 32 + nj * 16 + rf;
        float bm = WOb[col] + WOb[768 + col] + WOb[1536 + col] + WOb[2304 + col];
        #pragma unroll
        for (int mi = 0; mi < 2; mi++)
            #pragma unroll
            for (int r = 0; r < 4; r++) {
                int row = m0 + wm * 32 + mi * 16 + kg * 4 + r;
                Out[(size_t)row * 768 + col] = 0.25f * (acc[mi][nj][r] + bm);
            }
    }
}

// ---------------------------------------------------------------------------
extern "C" void kernel_launch(void* const* d_in, const int* in_sizes, int n_in,
                              void* d_out, int out_size, void* d_ws, size_t ws_size,
                              hipStream_t stream) {
    const float* A      = (const float*)d_in[0];
    const float* X      = (const float*)d_in[1];
    const float* WKw    = (const float*)d_in[2];
    const float* WKb    = (const float*)d_in[3];
    const float* WQw    = (const float*)d_in[4];
    const float* wA     = (const float*)d_in[5];
    const float* wB     = (const float*)d_in[6];
    const float* sink   = (const float*)d_in[7];
    const float* vnulls = (const float*)d_in[8];
    const float* V1w    = (const float*)d_in[9];
    const float* V1b    = (const float*)d_in[10];
    const float* V2w    = (const float*)d_in[11];
    const float* V2b    = (const float*)d_in[12];
    const float* WOw    = (const float*)d_in[13];
    const float* WOb    = (const float*)d_in[14];
    float* out = (float*)d_out;
    (void)in_sizes; (void)n_in; (void)out_size; (void)ws_size;

    float* ws = (float*)d_ws;
    size_t off = 0;
    float* Qr   = ws + off;  off += 6291456;   // head-major fp32 Q (rope'd)
    float* Kr   = ws + off;  off += 6291456;   // head-major fp32 K (rope'd)
    float* trig = ws + off;  off += 65536;
    float* bcat = ws + off;  off += 2048;
    float* O2   = ws + off;  off += 3145728;   // [2048][1536]: y | x
    float* Wsp_f = ws + off; off += 5308416;   // 3 planes x 4608x768 ushort
    unsigned short* Wsp = (unsigned short*)Wsp_f;
    unsigned short* Asp = (unsigned short*)(ws + off); off += 2359296;  // 3 planes x 2048x768
    unsigned short* Xsp = (unsigned short*)(ws + off); off += 2359296;
    unsigned short* V1b16 = (unsigned short*)(ws + off); off += 16384; // V1+V2 bf16 (dedicated)
    unsigned short* V2b16 = V1b16 + 16384;
    // overlays (dead-buffer reuse) — audited lifetimes:
    //   markerb = O2 (FULL 3,145,728 floats; O2 dead after k_finish)
    //   Kb16 = Wsp floats [0, 3145728); psink = Wsp floats [3145728, 3244032)
    unsigned short* markerb = (unsigned short*)O2;
    unsigned short* Kb16 = Wsp;
    float* psink = Wsp_f + 3145728;
    unsigned short* WOtb  = Asp;                         // Asp dead after proj
    unsigned short* ctxb  = (unsigned short*)Qr;         // Qr dead after attn

    // merged prep: trig + kbias + V cvt | weight fold/split | activation split
    prep_kernel<<<2024, 256, 0, stream>>>(trig, WKb, wA, bcat, V1w, V2w, V1b16,
                                          WQw, WKw, wB, Wsp, A, X, Asp, Xsp);
    // split-precision MFMA projection (round-14 single-buffer, 106 us)
    proj_mfma_kernel<<<576, 512, 0, stream>>>(Asp, Xsp, Wsp, bcat, trig, Qr, O2);
    // finish K: per-h bias wedge term + rope -> Kr fp32 + Kb16 bf16
    k_finish_kernel<<<3072, 256, 0, stream>>>(O2, trig, wB, Kr, Kb16);
    // attention: MFMA scores, fixed-offset softmax, bitonic top-8 shortlist,
    // exact fp32 top-4
    attn_mfma_topk_kernel<<<dim3(96, 8), 256, 0, stream>>>(Qr, Kr, Kb16, sink, markerb, psink);
    // post-top-k smooth path (bf16/MFMA)
    wo_transpose_kernel<<<dim3(12, 12, 4), 256, 0, stream>>>(WOw, WOtb);
    mlp_mfma_kernel<<<1536, 256, 0, stream>>>(markerb, psink, V1b16, V1b, V2b16, V2b, vnulls, ctxb);
    gemm_wo_mfma<<<dim3(32, 12), 256, 0, stream>>>(ctxb, WOtb, WOb, out);
}